// Round 7
// baseline (956.134 us; speedup 1.0000x reference)
//
#include <hip/hip_runtime.h>
#include <math.h>

#define N_NODES 16384
#define N_EDGES 131072
#define N_MOLS 512
#define HDIM 256
#define NLAYER 3
#define NRBF 50
#define CUT 5.0f
#define HH (HDIM*HDIM)

typedef unsigned short u16;
typedef __attribute__((ext_vector_type(8))) short short8v;
typedef __attribute__((ext_vector_type(4))) float f32x4;
typedef __attribute__((ext_vector_type(4))) unsigned short u16x4;
typedef __attribute__((ext_vector_type(8))) unsigned short u16x8;
typedef __attribute__((ext_vector_type(2))) unsigned short u16x2;

__device__ __forceinline__ float softplusf(float x){ return fmaxf(x,0.f)+log1pf(expf(-fabsf(x))); }
__device__ __forceinline__ float siluf(float x){ return x/(1.f+expf(-x)); }
__device__ __forceinline__ float bf2f(u16 u){ union{unsigned int i; float f;}v; v.i=((unsigned int)u)<<16; return v.f; }
__device__ __forceinline__ u16 f2bf(float f){ union{float f; unsigned int i;}v; v.f=f; unsigned int r = v.i + 0x7FFFu + ((v.i>>16)&1u); return (u16)(r>>16); }

__device__ __forceinline__ void gload_lds16(const void* g, void* l){
  __builtin_amdgcn_global_load_lds((const __attribute__((address_space(1))) unsigned int*)g,
                                   (__attribute__((address_space(3))) unsigned int*)l, 16, 0, 0);
}

// ---------------- CSR build ----------------
__global__ void k_hist(const int* __restrict__ dst, int* __restrict__ cnt){
  int e = blockIdx.x*256 + threadIdx.x;
  if(e < N_EDGES) atomicAdd(&cnt[dst[e]], 1);
}

__global__ __launch_bounds__(1024) void k_scan(const int* __restrict__ cnt,
                                               int* __restrict__ rowptr,
                                               int* __restrict__ cursor){
  __shared__ int part[1024];
  int tid = threadIdx.x;
  int base = tid*16;
  int loc[16]; int s=0;
  #pragma unroll
  for(int i=0;i<16;i++){ loc[i]=s; s+=cnt[base+i]; }
  part[tid]=s; __syncthreads();
  for(int off=1; off<1024; off<<=1){
    int v = (tid>=off)? part[tid-off] : 0;
    __syncthreads();
    part[tid] += v;
    __syncthreads();
  }
  int pre = (tid==0)?0:part[tid-1];
  #pragma unroll
  for(int i=0;i<16;i++){ int v = pre+loc[i]; rowptr[base+i]=v; cursor[base+i]=v; }
  if(tid==1023) rowptr[N_NODES]=part[1023];
}

__global__ void k_scatter(const int* __restrict__ dst, const int* __restrict__ src,
                          int* __restrict__ cursor,
                          int* __restrict__ perm, int* __restrict__ srcp){
  int e = blockIdx.x*256+threadIdx.x;
  if(e<N_EDGES){
    int p = atomicAdd(&cursor[dst[e]],1);
    perm[p]=e;
    srcp[p]=src[e];
  }
}

// ---------------- RBF in CSR order (bf16, padded to 64) ----------------
__global__ void k_rbf(const float* __restrict__ dist, const int* __restrict__ perm,
                      u16* __restrict__ rbfp){
  int gid = blockIdx.x*256+threadIdx.x;
  int i = gid>>6, r = gid&63;
  int e = perm[i];
  u16 o = 0;
  if(r<NRBF){
    float d = dist[e];
    float env = 0.5f*(cosf(3.14159265358979f*d/CUT)+1.f) * (d<CUT ? 1.f:0.f);
    float c = CUT*(float)r/(float)(NRBF-1);
    float u = (d - c)/(CUT/(float)NRBF);
    o = f2bf(expf(-0.5f*u*u)*env);
  }
  rbfp[(size_t)i*64+r] = o;
}

// ---------------- weight transpose+convert: W[K][256] f32 -> Wt[256][dK] bf16 ----------------
struct WDesc { const float* src; u16* dst; int K; int dK; };
struct WArgs { WDesc d[28]; };
__global__ __launch_bounds__(256) void k_wconv(WArgs a){
  WDesc w = a.d[blockIdx.x];
  int t = blockIdx.y;
  int ky = t >> 3, nx = t & 7;
  if(ky*32 >= w.dK) return;
  __shared__ float tile[32][33];
  int tid = threadIdx.x;
  int kk = tid >> 3, n4 = (tid & 7)*4;
  int k = ky*32 + kk;
  float4 v = {0.f,0.f,0.f,0.f};
  if(k < w.K) v = *(const float4*)(w.src + (size_t)k*HDIM + nx*32 + n4);
  tile[kk][n4+0]=v.x; tile[kk][n4+1]=v.y; tile[kk][n4+2]=v.z; tile[kk][n4+3]=v.w;
  __syncthreads();
  int nn = tid >> 3, k4 = (tid & 7)*4;
  u16x4 o;
  #pragma unroll
  for(int j=0;j<4;j++) o[j] = f2bf(tile[k4+j][nn]);
  *(u16x4*)(w.dst + (size_t)(nx*32+nn)*w.dK + ky*32 + k4) = o;
}

// ---------------- embedding ----------------
__global__ void k_embed(const float* __restrict__ at, const float* __restrict__ co,
                        const float* __restrict__ Wm, const float* __restrict__ bm,
                        const float* __restrict__ Wp, const float* __restrict__ bp,
                        float* __restrict__ mag, float* __restrict__ ph,
                        u16* __restrict__ magb, u16* __restrict__ phb){
  int n = blockIdx.x; int h = threadIdx.x;
  __shared__ float x[8];
  if(threadIdx.x<5) x[threadIdx.x] = at[n*5+threadIdx.x];
  else if(threadIdx.x<8) x[threadIdx.x] = co[n*3+threadIdx.x-5];
  __syncthreads();
  float tm=bm[h], tp=bp[h];
  #pragma unroll
  for(int i=0;i<8;i++){ tm = fmaf(x[i],Wm[i*HDIM+h],tm); tp = fmaf(x[i],Wp[i*HDIM+h],tp); }
  size_t idx = (size_t)n*HDIM+h;
  float m = softplusf(tm);
  float p = 3.14159265358979f*tanhf(tp);
  mag[idx]=m; ph[idx]=p; magb[idx]=f2bf(m); phb[idx]=f2bf(p);
}

// ---------------- MFMA GEMM body: C[M,ostr..] = A[M,K]bf16 @ Bt[256,K]bf16^T ----------------
// BM=128, BN=64, BK=64; 256 threads = 4 waves in 2(M)x2(N); wave tile 64x32.
// MODE 1: silu(x+bias)->bf16. 2: f32 += x+bias. 3: f32 = x+bias.
template<int MODE>
__device__ __forceinline__ void gemm_body(const u16* __restrict__ A,
                                          const u16* __restrict__ Bt,
                                          const float* __restrict__ bias,
                                          void* __restrict__ outp, int K, int ostr){
  __shared__ __align__(16) u16 As[128*64];
  __shared__ __align__(16) u16 Bs[64*64];
  int tid = threadIdx.x;
  int lane = tid & 63, wid = tid >> 6;
  int wm = wid & 1, wn = wid >> 1;
  int m0 = blockIdx.y * 128;
  int n0 = blockIdx.x * 64;
  const size_t Kb = (size_t)K*2;
  f32x4 acc[4][2] = {};
  for(int k0=0; k0<K; k0+=64){
    #pragma unroll
    for(int it=0; it<4; it++){
      int off = it*4096 + tid*16;
      int row = off >> 7, col = off & 127;
      const char* g = (const char*)A + (size_t)(m0+row)*Kb + (size_t)k0*2 + col;
      gload_lds16(g, (char*)As + it*4096 + wid*1024);
    }
    #pragma unroll
    for(int it=0; it<2; it++){
      int off = it*4096 + tid*16;
      int row = off >> 7, col = off & 127;
      const char* g = (const char*)Bt + (size_t)(n0+row)*Kb + (size_t)k0*2 + col;
      gload_lds16(g, (char*)Bs + it*4096 + wid*1024);
    }
    __syncthreads();
    #pragma unroll
    for(int ks=0; ks<2; ks++){
      int kl = ks*32 + (lane>>4)*8;
      short8v a[4], b[2];
      #pragma unroll
      for(int fm=0; fm<4; fm++){
        int m = wm*64 + fm*16 + (lane&15);
        a[fm] = *(const short8v*)&As[m*64 + kl];
      }
      #pragma unroll
      for(int fn=0; fn<2; fn++){
        int n = wn*32 + fn*16 + (lane&15);
        b[fn] = *(const short8v*)&Bs[n*64 + kl];
      }
      #pragma unroll
      for(int fm=0; fm<4; fm++)
        #pragma unroll
        for(int fn=0; fn<2; fn++)
          acc[fm][fn] = __builtin_amdgcn_mfma_f32_16x16x32_bf16(a[fm], b[fn], acc[fm][fn], 0,0,0);
    }
    __syncthreads();
  }
  int ro = (lane>>4)*4, co = lane&15;
  #pragma unroll
  for(int fm=0; fm<4; fm++){
    #pragma unroll
    for(int fn=0; fn<2; fn++){
      int col = n0 + wn*32 + fn*16 + co;
      float bv = bias ? bias[col] : 0.f;
      #pragma unroll
      for(int r=0; r<4; r++){
        int row = m0 + wm*64 + fm*16 + ro + r;
        float v = acc[fm][fn][r] + bv;
        size_t ci = (size_t)row*ostr + col;
        if(MODE==1) ((u16*)outp)[ci] = f2bf(siluf(v));
        else if(MODE==2) ((float*)outp)[ci] += v;
        else ((float*)outp)[ci] = v;
      }
    }
  }
}

// ---------------- fused pair GEMM for QKV with sincos epilogue ----------------
// z=0: qc,qs -> qpack[N][512]; z=1: kc,ks -> kvpack[N][1024]@0; z=2: vm,vp -> kvpack@512
struct Qkv2Args { const u16* Wm[3]; const u16* Wp[3]; u16* qpk; u16* kvpk; };
__global__ __launch_bounds__(256,2) void k_gemm_qkv2(const u16* __restrict__ magb,
                                                     const u16* __restrict__ phb,
                                                     Qkv2Args a){
  __shared__ __align__(16) u16 Am[128*64];
  __shared__ __align__(16) u16 Ap[128*64];
  __shared__ __align__(16) u16 Bm[64*64];
  __shared__ __align__(16) u16 Bp[64*64];
  int z = blockIdx.z;
  const u16* Wmz = a.Wm[z];
  const u16* Wpz = a.Wp[z];
  int tid = threadIdx.x;
  int lane = tid & 63, wid = tid >> 6;
  int wm = wid & 1, wn = wid >> 1;
  int m0 = blockIdx.y * 128;
  int n0 = blockIdx.x * 64;
  const size_t Kb = 512;  // K=256 bf16
  f32x4 accm[4][2] = {}, accp[4][2] = {};
  for(int k0=0; k0<256; k0+=64){
    #pragma unroll
    for(int it=0; it<4; it++){
      int off = it*4096 + tid*16;
      int row = off >> 7, col = off & 127;
      size_t go = (size_t)(m0+row)*Kb + (size_t)k0*2 + col;
      gload_lds16((const char*)magb + go, (char*)Am + it*4096 + wid*1024);
      gload_lds16((const char*)phb  + go, (char*)Ap + it*4096 + wid*1024);
    }
    #pragma unroll
    for(int it=0; it<2; it++){
      int off = it*4096 + tid*16;
      int row = off >> 7, col = off & 127;
      size_t go = (size_t)(n0+row)*Kb + (size_t)k0*2 + col;
      gload_lds16((const char*)Wmz + go, (char*)Bm + it*4096 + wid*1024);
      gload_lds16((const char*)Wpz + go, (char*)Bp + it*4096 + wid*1024);
    }
    __syncthreads();
    #pragma unroll
    for(int ks=0; ks<2; ks++){
      int kl = ks*32 + (lane>>4)*8;
      short8v am[4], ap[4], bm_[2], bp_[2];
      #pragma unroll
      for(int fm=0; fm<4; fm++){
        int m = wm*64 + fm*16 + (lane&15);
        am[fm] = *(const short8v*)&Am[m*64 + kl];
        ap[fm] = *(const short8v*)&Ap[m*64 + kl];
      }
      #pragma unroll
      for(int fn=0; fn<2; fn++){
        int n = wn*32 + fn*16 + (lane&15);
        bm_[fn] = *(const short8v*)&Bm[n*64 + kl];
        bp_[fn] = *(const short8v*)&Bp[n*64 + kl];
      }
      #pragma unroll
      for(int fm=0; fm<4; fm++)
        #pragma unroll
        for(int fn=0; fn<2; fn++){
          accm[fm][fn] = __builtin_amdgcn_mfma_f32_16x16x32_bf16(am[fm], bm_[fn], accm[fm][fn], 0,0,0);
          accp[fm][fn] = __builtin_amdgcn_mfma_f32_16x16x32_bf16(ap[fm], bp_[fn], accp[fm][fn], 0,0,0);
        }
    }
    __syncthreads();
  }
  int ro = (lane>>4)*4, co = lane&15;
  #pragma unroll
  for(int fm=0; fm<4; fm++){
    #pragma unroll
    for(int fn=0; fn<2; fn++){
      int col = n0 + wn*32 + fn*16 + co;
      #pragma unroll
      for(int r=0; r<4; r++){
        int row = m0 + wm*64 + fm*16 + ro + r;
        float mv = accm[fm][fn][r];
        float pv = accp[fm][fn][r];
        u16 o0, o1;
        if(z<2){
          float sn, cs;
          __sincosf(pv, &sn, &cs);
          o0 = f2bf(mv*cs); o1 = f2bf(mv*sn);
        } else {
          o0 = f2bf(mv); o1 = f2bf(pv);
        }
        u16* base = (z==0) ? (a.qpk + (size_t)row*512)
                           : (a.kvpk + (size_t)row*1024 + (z==2 ? 512 : 0));
        base[col] = o0;
        base[col+256] = o1;
      }
    }
  }
}

__global__ __launch_bounds__(256,2) void k_gemm_gate(const u16* __restrict__ rbfp,
                                                     const u16* __restrict__ Wt,
                                                     const float* __restrict__ be,
                                                     u16* __restrict__ gate){
  gemm_body<1>(rbfp, Wt, be, gate, 64, 256);
}
struct MpArgs { const u16* A[2]; const u16* Wt[2]; const float* b[2]; float* C[2]; };
__global__ __launch_bounds__(256,2) void k_gemm_mp(MpArgs a){
  int z = blockIdx.z;
  gemm_body<2>(a.A[z], a.Wt[z], a.b[z], a.C[z], HDIM, 256);
}
__global__ __launch_bounds__(256,2) void k_gemm_proj(const u16* __restrict__ Ab,
                                                     const u16* __restrict__ Wt,
                                                     const float* __restrict__ b,
                                                     float* __restrict__ C){
  gemm_body<3>(Ab, Wt, b, C, HDIM, 256);
}

// ---------------- fused attention v3: cos-decomposed scores, streaming metadata ----------------
// wave per dst node; half-wave owns alternate edges; lane owns 8 channels.
__global__ __launch_bounds__(256) void k_attn_fused(
    const int* __restrict__ rowptr, const int* __restrict__ srcp,
    const u16* __restrict__ qpack, const u16* __restrict__ kvpack,
    const u16* __restrict__ rbfp,
    const float* __restrict__ We, const float* __restrict__ be,
    float* __restrict__ nmag, float* __restrict__ nph,
    u16* __restrict__ npack)
{
  int wid = threadIdx.x >> 6, lane = threadIdx.x & 63;
  int hid = lane >> 5, l = lane & 31;
  int d = blockIdx.x*4 + wid;
  int b = rowptr[d], e = rowptr[d+1];
  const u16* qb = qpack + (size_t)d*512 + l*8;
  u16x8 qc8 = *(const u16x8*)qb;
  u16x8 qs8 = *(const u16x8*)(qb + 256);
  float qcf[8], qsf[8];
  #pragma unroll
  for(int j=0;j<8;j++){ qcf[j]=bf2f(qc8[j]); qsf[j]=bf2f(qs8[j]); }
  float We0 = (2*l   < NRBF) ? We[2*l]   : 0.f;
  float We1 = (2*l+1 < NRBF) ? We[2*l+1] : 0.f;
  float be0 = be[0];
  float z = 0.f;
  float avm[8] = {0,0,0,0,0,0,0,0}, avp[8] = {0,0,0,0,0,0,0,0};
  for(int i = b + hid; i < e; i += 2){
    int s = srcp[i];
    const u16* kb = kvpack + (size_t)s*1024 + l*8;
    u16x8 kc8 = *(const u16x8*)kb;
    u16x8 ks8 = *(const u16x8*)(kb + 256);
    u16x8 vm8 = *(const u16x8*)(kb + 512);
    u16x8 vp8 = *(const u16x8*)(kb + 768);
    u16x2 rb2 = *(const u16x2*)(rbfp + (size_t)i*64 + 2*l);
    float p = 0.f;
    #pragma unroll
    for(int j=0;j<8;j++){
      p = fmaf(qcf[j], bf2f(kc8[j]), p);
      p = fmaf(qsf[j], bf2f(ks8[j]), p);
    }
    float t = fmaf(bf2f(rb2[0]), We0, fmaf(bf2f(rb2[1]), We1, p*0.0625f));
    #pragma unroll
    for(int off=16; off; off>>=1) t += __shfl_xor(t, off, 64);
    float w = __expf(t + be0);   // scores O(1): softmax shift-invariant, no max needed
    z += w;
    #pragma unroll
    for(int j=0;j<8;j++){
      avm[j] = fmaf(w, bf2f(vm8[j]), avm[j]);
      avp[j] = fmaf(w, bf2f(vp8[j]), avp[j]);
    }
  }
  z += __shfl_xor(z, 32, 64);
  #pragma unroll
  for(int j=0;j<8;j++){
    avm[j] += __shfl_xor(avm[j], 32, 64);
    avp[j] += __shfl_xor(avp[j], 32, 64);
  }
  if(hid==0){
    float inv = 1.f/(z + 1e-9f);
    u16x8 mb, pb;
    #pragma unroll
    for(int j=0;j<8;j++){ avm[j]*=inv; avp[j]*=inv; mb[j]=f2bf(avm[j]); pb[j]=f2bf(avp[j]); }
    size_t no = (size_t)d*256 + l*8;
    *(float4*)(nmag + no)     = make_float4(avm[0],avm[1],avm[2],avm[3]);
    *(float4*)(nmag + no + 4) = make_float4(avm[4],avm[5],avm[6],avm[7]);
    *(float4*)(nph + no)      = make_float4(avp[0],avp[1],avp[2],avp[3]);
    *(float4*)(nph + no + 4)  = make_float4(avp[4],avp[5],avp[6],avp[7]);
    u16* nb = npack + (size_t)d*512 + l*8;
    *(u16x8*)nb = mb;
    *(u16x8*)(nb + 256) = pb;
  }
}

// ---------------- message passing aggregation v3 (streaming gate, packed gathers) ----------------
__global__ __launch_bounds__(256) void k_mp_agg(const int* __restrict__ rowptr,
                         const int* __restrict__ srcp, const u16* __restrict__ gate,
                         const u16* __restrict__ npack,
                         u16* __restrict__ aggm, u16* __restrict__ aggp){
  int wid = threadIdx.x >> 6, lane = threadIdx.x & 63;
  int hid = lane >> 5, l = lane & 31;
  int n = blockIdx.x*4 + wid;
  int b = rowptr[n], e = rowptr[n+1];
  float am[8] = {0,0,0,0,0,0,0,0}, ap[8] = {0,0,0,0,0,0,0,0};
  for(int i = b + hid; i < e; i += 2){
    int s = srcp[i];
    u16x8 g8 = *(const u16x8*)(gate + (size_t)i*256 + l*8);
    const u16* nb = npack + (size_t)s*512 + l*8;
    u16x8 m8 = *(const u16x8*)nb;
    u16x8 p8 = *(const u16x8*)(nb + 256);
    #pragma unroll
    for(int j=0;j<8;j++){
      float g = bf2f(g8[j]);
      am[j] = fmaf(g, bf2f(m8[j]), am[j]);
      ap[j] = fmaf(g, bf2f(p8[j]), ap[j]);
    }
  }
  #pragma unroll
  for(int j=0;j<8;j++){
    am[j] += __shfl_xor(am[j], 32, 64);
    ap[j] += __shfl_xor(ap[j], 32, 64);
  }
  if(hid==0){
    u16x8 amb, apb;
    #pragma unroll
    for(int j=0;j<8;j++){ amb[j]=f2bf(am[j]); apb[j]=f2bf(ap[j]); }
    size_t o = (size_t)n*256 + l*8;
    *(u16x8*)(aggm + o) = amb;
    *(u16x8*)(aggp + o) = apb;
  }
}

// ---------------- residual + LayerNorm (LAST fuses mag*cos(ph) projection input) ----------------
template<int LAST>
__global__ __launch_bounds__(256) void k_resid_ln(const float* __restrict__ nmag, const float* __restrict__ nph,
                           float* __restrict__ mag, float* __restrict__ ph,
                           u16* __restrict__ magb, u16* __restrict__ phb,
                           u16* __restrict__ tcosb,
                           const float* __restrict__ g, const float* __restrict__ b){
  int n = blockIdx.x, tid = threadIdx.x;
  size_t idx = (size_t)n*HDIM+tid;
  float t = nmag[idx] + mag[idx];
  float s1=t, s2=t*t;
  #pragma unroll
  for(int off=32; off; off>>=1){ s1 += __shfl_down(s1,off,64); s2 += __shfl_down(s2,off,64); }
  __shared__ float w1[4], w2[4], bc[2];
  int wid = tid>>6, lane = tid&63;
  if(lane==0){ w1[wid]=s1; w2[wid]=s2; }
  __syncthreads();
  if(tid==0){
    float a=w1[0]+w1[1]+w1[2]+w1[3];
    float q=w2[0]+w2[1]+w2[2]+w2[3];
    float mu = a*(1.f/HDIM);
    float var = q*(1.f/HDIM) - mu*mu;
    bc[0]=mu; bc[1]=rsqrtf(var+1e-5f);
  }
  __syncthreads();
  float mu=bc[0], rs=bc[1];
  float ln = (t-mu)*rs*g[tid]+b[tid];
  float p2 = nph[idx] + ph[idx];
  if(LAST){
    tcosb[idx] = f2bf(ln*__cosf(p2));
  } else {
    mag[idx] = ln; magb[idx] = f2bf(ln);
    ph[idx] = p2; phb[idx] = f2bf(p2);
  }
}

// ---------------- pooling ----------------
__global__ void k_pool(const float* __restrict__ arepr, const int* __restrict__ n2m,
                       float* __restrict__ spool, float* __restrict__ cntf){
  int gid = blockIdx.x*256+threadIdx.x;
  int n = gid>>8, h = gid&255;
  int m = n2m[n];
  atomicAdd(&spool[(size_t)m*HDIM+h], arepr[(size_t)n*HDIM+h]);
  if(h==0) atomicAdd(&cntf[m], 1.f);
}

// ---------------- head MLP ----------------
__global__ __launch_bounds__(256) void k_head(const float* __restrict__ spool, const float* __restrict__ cntf,
                       const float* __restrict__ W1, const float* __restrict__ b1,
                       const float* __restrict__ W2, const float* __restrict__ b2,
                       const float* __restrict__ W3, const float* __restrict__ b3,
                       float* __restrict__ out){
  __shared__ float smol[2*HDIM];
  __shared__ float sh1[HDIM];
  __shared__ float sh2[HDIM/2];
  int m = blockIdx.x, tid = threadIdx.x;
  float sv = spool[(size_t)m*HDIM+tid];
  float c = cntf[m];
  smol[tid] = sv/fmaxf(c,1.f);
  smol[HDIM+tid] = sv;
  __syncthreads();
  float a = b1[tid];
  for(int i=0;i<2*HDIM;i++) a = fmaf(smol[i], W1[i*HDIM+tid], a);
  sh1[tid] = siluf(a);
  __syncthreads();
  if(tid<128){
    float a2 = b2[tid];
    for(int i=0;i<HDIM;i++) a2 = fmaf(sh1[i], W2[i*128+tid], a2);
    sh2[tid] = siluf(a2);
  }
  __syncthreads();
  if(tid<64){
    float p = sh2[tid]*W3[tid] + sh2[tid+64]*W3[tid+64];
    #pragma unroll
    for(int off=32; off; off>>=1) p += __shfl_down(p,off,64);
    if(tid==0) out[m] = p + b3[0];
  }
}

extern "C" void kernel_launch(void* const* d_in, const int* in_sizes, int n_in,
                              void* d_out, int out_size, void* d_ws, size_t ws_size,
                              hipStream_t stream){
  const float* atom_types = (const float*)d_in[0];
  const float* coords     = (const float*)d_in[1];
  const float* edge_dist  = (const float*)d_in[2];
  const int*   edge_index = (const int*)d_in[3];
  const int*   node2mol   = (const int*)d_in[4];
  const float* emb_Wm = (const float*)d_in[5];
  const float* emb_bm = (const float*)d_in[6];
  const float* emb_Wp = (const float*)d_in[7];
  const float* emb_bp = (const float*)d_in[8];
  const float* attn_Wqm = (const float*)d_in[9];
  const float* attn_Wkm = (const float*)d_in[10];
  const float* attn_Wvm = (const float*)d_in[11];
  const float* attn_Wqp = (const float*)d_in[12];
  const float* attn_Wkp = (const float*)d_in[13];
  const float* attn_Wvp = (const float*)d_in[14];
  const float* attn_We  = (const float*)d_in[15];
  const float* attn_be  = (const float*)d_in[16];
  const float* mp_We = (const float*)d_in[17];
  const float* mp_be = (const float*)d_in[18];
  const float* mp_Wm = (const float*)d_in[19];
  const float* mp_bm = (const float*)d_in[20];
  const float* mp_Wp = (const float*)d_in[21];
  const float* mp_bp = (const float*)d_in[22];
  const float* ln_g = (const float*)d_in[23];
  const float* ln_b = (const float*)d_in[24];
  const float* proj_W = (const float*)d_in[25];
  const float* proj_b = (const float*)d_in[26];
  const float* head_W1 = (const float*)d_in[27];
  const float* head_b1 = (const float*)d_in[28];
  const float* head_W2 = (const float*)d_in[29];
  const float* head_b2 = (const float*)d_in[30];
  const float* head_W3 = (const float*)d_in[31];
  const float* head_b3 = (const float*)d_in[32];
  float* out = (float*)d_out;

  float* ws = (float*)d_ws;
  const size_t NH = (size_t)N_NODES*HDIM;
  size_t o = 0;
  float* mag = ws + o; o += NH;
  float* ph  = ws + o; o += NH;
  float* nmag= ws + o; o += NH;
  float* nph = ws + o; o += NH;
  float* spool = ws + o; o += (size_t)N_MOLS*HDIM;
  float* cntf  = ws + o; o += N_MOLS;
  int* rowptr = (int*)(ws + o); o += N_NODES+1;
  int* cnt    = (int*)(ws + o); o += N_NODES;
  int* cursor = (int*)(ws + o); o += N_NODES;
  int* perm   = (int*)(ws + o); o += N_EDGES;
  int* srcp   = (int*)(ws + o); o += N_EDGES + 1;   // +1 keeps 8B alignment after
  u16* magb = (u16*)(ws + o); o += NH/2;
  u16* phb  = (u16*)(ws + o); o += NH/2;
  u16* aggmb= (u16*)(ws + o); o += NH/2;
  u16* aggpb= (u16*)(ws + o); o += NH/2;
  u16* npack= (u16*)(ws + o); o += NH;                        // [N][512] bf16 (mag|ph)
  u16* rbfp = (u16*)(ws + o); o += (size_t)N_EDGES*32;        // [E][64] bf16, CSR order
  u16* qpack= (u16*)(ws + o); o += NH;                        // [N][512] bf16 (qc|qs)
  u16* kvpack=(u16*)(ws + o); o += 2*NH;                      // [N][1024] bf16 (kc|ks|vm|vp)
  o += NH;                                                    // pad: gatep tail
  u16* wt   = (u16*)(ws + o); o += (25*(size_t)HH + 3*HDIM*64)/2;
  u16* gatep = qpack;      // [E][256] bf16 CSR order; aliases qpack+kvpack+pad (disjoint lifetime)
  float* arepr = nmag;     // free after last resid_ln
  u16* tcosb = aggmb;      // free after last mp gemm

  const int* src = edge_index;
  const int* dst = edge_index + N_EDGES;

  // ---- weight convert/transpose descriptors ----
  WArgs wa;
  for(int l=0;l<NLAYER;l++){
    const float* srcs[6] = {attn_Wqm+(size_t)l*HH, attn_Wkm+(size_t)l*HH, attn_Wvm+(size_t)l*HH,
                            attn_Wqp+(size_t)l*HH, attn_Wkp+(size_t)l*HH, attn_Wvp+(size_t)l*HH};
    for(int j=0;j<6;j++){ wa.d[l*6+j] = { srcs[j], wt + (size_t)(l*6+j)*HH, HDIM, HDIM }; }
    wa.d[18+l] = { mp_Wm+(size_t)l*HH, wt + (size_t)(18+l)*HH, HDIM, HDIM };
    wa.d[21+l] = { mp_Wp+(size_t)l*HH, wt + (size_t)(21+l)*HH, HDIM, HDIM };
    wa.d[25+l] = { mp_We+(size_t)l*NRBF*HDIM, wt + (size_t)25*HH + (size_t)l*HDIM*64, NRBF, 64 };
  }
  wa.d[24] = { proj_W, wt + (size_t)24*HH, HDIM, HDIM };

  hipMemsetAsync(cnt, 0, N_NODES*sizeof(int), stream);
  k_hist<<<N_EDGES/256,256,0,stream>>>(dst, cnt);
  k_scan<<<1,1024,0,stream>>>(cnt, rowptr, cursor);
  k_scatter<<<N_EDGES/256,256,0,stream>>>(dst, src, cursor, perm, srcp);
  k_wconv<<<dim3(28,64),256,0,stream>>>(wa);
  k_rbf<<<(N_EDGES*64)/256,256,0,stream>>>(edge_dist, perm, rbfp);
  k_embed<<<N_NODES,256,0,stream>>>(atom_types, coords, emb_Wm, emb_bm, emb_Wp, emb_bp,
                                    mag, ph, magb, phb);

  dim3 gn(HDIM/64, N_NODES/128);       // node gemms: (4, 128)
  dim3 ge(HDIM/64, N_EDGES/128);       // gate gemm: (4, 1024)
  for(int l=0;l<NLAYER;l++){
    Qkv2Args qa;
    qa.Wm[0] = wt + (size_t)(l*6+0)*HH;  // Wqm
    qa.Wm[1] = wt + (size_t)(l*6+1)*HH;  // Wkm
    qa.Wm[2] = wt + (size_t)(l*6+2)*HH;  // Wvm
    qa.Wp[0] = wt + (size_t)(l*6+3)*HH;  // Wqp
    qa.Wp[1] = wt + (size_t)(l*6+4)*HH;  // Wkp
    qa.Wp[2] = wt + (size_t)(l*6+5)*HH;  // Wvp
    qa.qpk = qpack; qa.kvpk = kvpack;
    k_gemm_qkv2<<<dim3(4,128,3),256,0,stream>>>(magb, phb, qa);
    k_attn_fused<<<N_NODES/4,256,0,stream>>>(rowptr, srcp, qpack, kvpack,
                                             rbfp, attn_We+(size_t)l*NRBF, attn_be+l,
                                             nmag, nph, npack);
    k_gemm_gate<<<ge,256,0,stream>>>(rbfp, wt + (size_t)25*HH + (size_t)l*HDIM*64,
                                     mp_be+(size_t)l*HDIM, gatep);
    k_mp_agg<<<N_NODES/4,256,0,stream>>>(rowptr, srcp, gatep, npack, aggmb, aggpb);
    MpArgs ma;
    ma.A[0]=aggmb; ma.A[1]=aggpb;
    ma.Wt[0]=wt + (size_t)(18+l)*HH; ma.Wt[1]=wt + (size_t)(21+l)*HH;
    ma.b[0]=mp_bm+(size_t)l*HDIM; ma.b[1]=mp_bp+(size_t)l*HDIM;
    ma.C[0]=nmag; ma.C[1]=nph;
    k_gemm_mp<<<dim3(4,128,2),256,0,stream>>>(ma);
    if(l < NLAYER-1)
      k_resid_ln<0><<<N_NODES,256,0,stream>>>(nmag, nph, mag, ph, magb, phb, nullptr,
                                              ln_g+(size_t)l*HDIM, ln_b+(size_t)l*HDIM);
    else
      k_resid_ln<1><<<N_NODES,256,0,stream>>>(nmag, nph, mag, ph, magb, phb, tcosb,
                                              ln_g+(size_t)l*HDIM, ln_b+(size_t)l*HDIM);
  }
  k_gemm_proj<<<gn,256,0,stream>>>(tcosb, wt + (size_t)24*HH, proj_b, arepr);
  hipMemsetAsync(spool, 0, ((size_t)N_MOLS*HDIM+N_MOLS)*sizeof(float), stream);
  k_pool<<<NH/256,256,0,stream>>>(arepr, node2mol, spool, cntf);
  k_head<<<N_MOLS,256,0,stream>>>(spool, cntf, head_W1, head_b1, head_W2, head_b2, head_W3, head_b3, out);
}

// Round 8
// 855.071 us; speedup vs baseline: 1.1182x; 1.1182x over previous
//
#include <hip/hip_runtime.h>
#include <math.h>

#define N_NODES 16384
#define N_EDGES 131072
#define N_MOLS 512
#define HDIM 256
#define NLAYER 3
#define NRBF 50
#define CUT 5.0f
#define HH (HDIM*HDIM)

typedef unsigned short u16;
typedef __attribute__((ext_vector_type(8))) short short8v;
typedef __attribute__((ext_vector_type(4))) float f32x4;
typedef __attribute__((ext_vector_type(4))) unsigned short u16x4;
typedef __attribute__((ext_vector_type(8))) unsigned short u16x8;
typedef __attribute__((ext_vector_type(2))) unsigned short u16x2;

__device__ __forceinline__ float softplusf(float x){ return fmaxf(x,0.f)+log1pf(expf(-fabsf(x))); }
__device__ __forceinline__ float siluf(float x){ return x/(1.f+expf(-x)); }
__device__ __forceinline__ float bf2f(u16 u){ union{unsigned int i; float f;}v; v.i=((unsigned int)u)<<16; return v.f; }
__device__ __forceinline__ u16 f2bf(float f){ union{float f; unsigned int i;}v; v.f=f; unsigned int r = v.i + 0x7FFFu + ((v.i>>16)&1u); return (u16)(r>>16); }

__device__ __forceinline__ void gload_lds16(const void* g, void* l){
  __builtin_amdgcn_global_load_lds((const __attribute__((address_space(1))) unsigned int*)g,
                                   (__attribute__((address_space(3))) unsigned int*)l, 16, 0, 0);
}

// ---------------- CSR build ----------------
__global__ void k_hist(const int* __restrict__ dst, int* __restrict__ cnt){
  int e = blockIdx.x*256 + threadIdx.x;
  if(e < N_EDGES) atomicAdd(&cnt[dst[e]], 1);
}

__global__ __launch_bounds__(1024) void k_scan(const int* __restrict__ cnt,
                                               int* __restrict__ rowptr,
                                               int* __restrict__ cursor){
  __shared__ int part[1024];
  int tid = threadIdx.x;
  int base = tid*16;
  int loc[16]; int s=0;
  #pragma unroll
  for(int i=0;i<16;i++){ loc[i]=s; s+=cnt[base+i]; }
  part[tid]=s; __syncthreads();
  for(int off=1; off<1024; off<<=1){
    int v = (tid>=off)? part[tid-off] : 0;
    __syncthreads();
    part[tid] += v;
    __syncthreads();
  }
  int pre = (tid==0)?0:part[tid-1];
  #pragma unroll
  for(int i=0;i<16;i++){ int v = pre+loc[i]; rowptr[base+i]=v; cursor[base+i]=v; }
  if(tid==1023) rowptr[N_NODES]=part[1023];
}

__global__ void k_scatter(const int* __restrict__ dst, const int* __restrict__ src,
                          int* __restrict__ cursor,
                          int* __restrict__ perm, int* __restrict__ srcp){
  int e = blockIdx.x*256+threadIdx.x;
  if(e<N_EDGES){
    int p = atomicAdd(&cursor[dst[e]],1);
    perm[p]=e;
    srcp[p]=src[e];
  }
}

// ---------------- RBF in CSR order (bf16, padded to 64) ----------------
__global__ void k_rbf(const float* __restrict__ dist, const int* __restrict__ perm,
                      u16* __restrict__ rbfp){
  int gid = blockIdx.x*256+threadIdx.x;
  int i = gid>>6, r = gid&63;
  int e = perm[i];
  u16 o = 0;
  if(r<NRBF){
    float d = dist[e];
    float env = 0.5f*(cosf(3.14159265358979f*d/CUT)+1.f) * (d<CUT ? 1.f:0.f);
    float c = CUT*(float)r/(float)(NRBF-1);
    float u = (d - c)/(CUT/(float)NRBF);
    o = f2bf(expf(-0.5f*u*u)*env);
  }
  rbfp[(size_t)i*64+r] = o;
}

// ---------------- weight transpose+convert: W[K][256] f32 -> Wt[256][dK] bf16 ----------------
struct WDesc { const float* src; u16* dst; int K; int dK; };
struct WArgs { WDesc d[28]; };
__global__ __launch_bounds__(256) void k_wconv(WArgs a){
  WDesc w = a.d[blockIdx.x];
  int t = blockIdx.y;
  int ky = t >> 3, nx = t & 7;
  if(ky*32 >= w.dK) return;
  __shared__ float tile[32][33];
  int tid = threadIdx.x;
  int kk = tid >> 3, n4 = (tid & 7)*4;
  int k = ky*32 + kk;
  float4 v = {0.f,0.f,0.f,0.f};
  if(k < w.K) v = *(const float4*)(w.src + (size_t)k*HDIM + nx*32 + n4);
  tile[kk][n4+0]=v.x; tile[kk][n4+1]=v.y; tile[kk][n4+2]=v.z; tile[kk][n4+3]=v.w;
  __syncthreads();
  int nn = tid >> 3, k4 = (tid & 7)*4;
  u16x4 o;
  #pragma unroll
  for(int j=0;j<4;j++) o[j] = f2bf(tile[k4+j][nn]);
  *(u16x4*)(w.dst + (size_t)(nx*32+nn)*w.dK + ky*32 + k4) = o;
}

// ---------------- embedding ----------------
__global__ void k_embed(const float* __restrict__ at, const float* __restrict__ co,
                        const float* __restrict__ Wm, const float* __restrict__ bm,
                        const float* __restrict__ Wp, const float* __restrict__ bp,
                        float* __restrict__ mag, float* __restrict__ ph,
                        u16* __restrict__ magb, u16* __restrict__ phb){
  int n = blockIdx.x; int h = threadIdx.x;
  __shared__ float x[8];
  if(threadIdx.x<5) x[threadIdx.x] = at[n*5+threadIdx.x];
  else if(threadIdx.x<8) x[threadIdx.x] = co[n*3+threadIdx.x-5];
  __syncthreads();
  float tm=bm[h], tp=bp[h];
  #pragma unroll
  for(int i=0;i<8;i++){ tm = fmaf(x[i],Wm[i*HDIM+h],tm); tp = fmaf(x[i],Wp[i*HDIM+h],tp); }
  size_t idx = (size_t)n*HDIM+h;
  float m = softplusf(tm);
  float p = 3.14159265358979f*tanhf(tp);
  mag[idx]=m; ph[idx]=p; magb[idx]=f2bf(m); phb[idx]=f2bf(p);
}

// ======== full-N GEMM: 512 thr, BM=128, BN=256(whole width), BK=64 ========
// waves 2(M)x4(N), wave tile 64x64. A read ONCE per block (no N-split refetch).
// XOR chunk swizzle: LDS linear dest, global source chunk ^= row&7, ds_read chunk ^= row&7.
// MODE 1: silu(x+bias)->bf16. 2: f32 += x+bias. 3: f32 = x+bias.
template<int MODE>
__device__ __forceinline__ void gemm_fullN(const u16* __restrict__ A,
                                           const u16* __restrict__ Bt,
                                           const float* __restrict__ bias,
                                           void* __restrict__ outp, int K){
  __shared__ __align__(16) u16 As[128*64];
  __shared__ __align__(16) u16 Bs[256*64];
  int tid = threadIdx.x;
  int lane = tid & 63, wid = tid >> 6;
  int wm = wid & 1, wn = wid >> 1;
  int m0 = blockIdx.y * 128;
  const size_t Kb = (size_t)K*2;
  f32x4 acc[4][4] = {};
  for(int k0=0;k0<K;k0+=64){
    #pragma unroll
    for(int it=0; it<2; it++){
      int ci = it*512 + tid;
      int row = ci>>3, cl = ci&7;
      int csw = cl ^ (row&7);
      size_t go = (size_t)(m0+row)*Kb + (size_t)k0*2 + csw*16;
      gload_lds16((const char*)A+go, (char*)As + it*8192 + wid*1024);
    }
    #pragma unroll
    for(int it=0; it<4; it++){
      int ci = it*512 + tid;
      int row = ci>>3, cl = ci&7;
      int csw = cl ^ (row&7);
      size_t go = (size_t)row*Kb + (size_t)k0*2 + csw*16;
      gload_lds16((const char*)Bt+go, (char*)Bs + it*8192 + wid*1024);
    }
    __syncthreads();
    #pragma unroll
    for(int ks=0;ks<2;ks++){
      short8v a[4], b[4];
      #pragma unroll
      for(int fm=0;fm<4;fm++){
        int m = wm*64 + fm*16 + (lane&15);
        int ch = (ks*4 + (lane>>4)) ^ (m&7);
        a[fm] = *(const short8v*)&As[m*64 + ch*8];
      }
      #pragma unroll
      for(int fn=0;fn<4;fn++){
        int n = wn*64 + fn*16 + (lane&15);
        int ch = (ks*4 + (lane>>4)) ^ (n&7);
        b[fn] = *(const short8v*)&Bs[n*64 + ch*8];
      }
      #pragma unroll
      for(int fm=0;fm<4;fm++)
        #pragma unroll
        for(int fn=0;fn<4;fn++)
          acc[fm][fn] = __builtin_amdgcn_mfma_f32_16x16x32_bf16(a[fm], b[fn], acc[fm][fn],0,0,0);
    }
    __syncthreads();
  }
  int ro=(lane>>4)*4, co=lane&15;
  #pragma unroll
  for(int fm=0;fm<4;fm++){
    #pragma unroll
    for(int fn=0;fn<4;fn++){
      int col = wn*64 + fn*16 + co;
      float bv = bias ? bias[col] : 0.f;
      #pragma unroll
      for(int r=0;r<4;r++){
        int row = m0 + wm*64 + fm*16 + ro + r;
        float v = acc[fm][fn][r] + bv;
        size_t ci = (size_t)row*256 + col;
        if(MODE==1) ((u16*)outp)[ci] = f2bf(siluf(v));
        else if(MODE==2) ((float*)outp)[ci] += v;
        else ((float*)outp)[ci] = v;
      }
    }
  }
}

__global__ __launch_bounds__(512) void k_gemm_gate(const u16* __restrict__ rbfp,
                                                   const u16* __restrict__ Wt,
                                                   const float* __restrict__ be,
                                                   u16* __restrict__ gate){
  gemm_fullN<1>(rbfp, Wt, be, gate, 64);
}
struct MpArgs { const u16* A[2]; const u16* Wt[2]; const float* b[2]; float* C[2]; };
__global__ __launch_bounds__(512) void k_gemm_mp(MpArgs a){
  int z = blockIdx.z;
  gemm_fullN<2>(a.A[z], a.Wt[z], a.b[z], a.C[z], HDIM);
}
__global__ __launch_bounds__(512) void k_gemm_proj(const u16* __restrict__ Ab,
                                                   const u16* __restrict__ Wt,
                                                   const float* __restrict__ b,
                                                   float* __restrict__ C){
  gemm_fullN<3>(Ab, Wt, b, C, HDIM);
}

// ======== full-N PAIR GEMM for QKV (mag & ph together) + sincos epilogue ========
// z=0: qc,qs -> qpack[N][512]; z=1: kc,ks -> kvpack[N][1024]@0; z=2: vm,vp -> kvpack@512
struct Qkv3Args { const u16* Wm[3]; const u16* Wp[3]; u16* qpk; u16* kvpk; };
__global__ __launch_bounds__(512) void k_gemm_qkv3(const u16* __restrict__ magb,
                                                   const u16* __restrict__ phb,
                                                   Qkv3Args a){
  __shared__ __align__(16) u16 Ams[128*64];
  __shared__ __align__(16) u16 Aps[128*64];
  __shared__ __align__(16) u16 Bms[256*64];
  __shared__ __align__(16) u16 Bps[256*64];
  int z = blockIdx.z;
  const u16* Wmz = a.Wm[z];
  const u16* Wpz = a.Wp[z];
  int tid = threadIdx.x;
  int lane = tid & 63, wid = tid >> 6;
  int wm = wid & 1, wn = wid >> 1;
  int m0 = blockIdx.y * 128;
  const size_t Kb = 512;  // K=256 bf16
  f32x4 accm[4][4] = {}, accp[4][4] = {};
  for(int k0=0;k0<256;k0+=64){
    #pragma unroll
    for(int it=0; it<2; it++){
      int ci = it*512 + tid;
      int row = ci>>3, cl = ci&7;
      int csw = cl ^ (row&7);
      size_t go = (size_t)(m0+row)*Kb + (size_t)k0*2 + csw*16;
      gload_lds16((const char*)magb+go, (char*)Ams + it*8192 + wid*1024);
      gload_lds16((const char*)phb +go, (char*)Aps + it*8192 + wid*1024);
    }
    #pragma unroll
    for(int it=0; it<4; it++){
      int ci = it*512 + tid;
      int row = ci>>3, cl = ci&7;
      int csw = cl ^ (row&7);
      size_t go = (size_t)row*Kb + (size_t)k0*2 + csw*16;
      gload_lds16((const char*)Wmz+go, (char*)Bms + it*8192 + wid*1024);
      gload_lds16((const char*)Wpz+go, (char*)Bps + it*8192 + wid*1024);
    }
    __syncthreads();
    #pragma unroll
    for(int ks=0;ks<2;ks++){
      short8v am[4], ap[4], bm_[4], bp_[4];
      #pragma unroll
      for(int fm=0;fm<4;fm++){
        int m = wm*64 + fm*16 + (lane&15);
        int ch = (ks*4 + (lane>>4)) ^ (m&7);
        am[fm] = *(const short8v*)&Ams[m*64 + ch*8];
        ap[fm] = *(const short8v*)&Aps[m*64 + ch*8];
      }
      #pragma unroll
      for(int fn=0;fn<4;fn++){
        int n = wn*64 + fn*16 + (lane&15);
        int ch = (ks*4 + (lane>>4)) ^ (n&7);
        bm_[fn] = *(const short8v*)&Bms[n*64 + ch*8];
        bp_[fn] = *(const short8v*)&Bps[n*64 + ch*8];
      }
      #pragma unroll
      for(int fm=0;fm<4;fm++)
        #pragma unroll
        for(int fn=0;fn<4;fn++){
          accm[fm][fn] = __builtin_amdgcn_mfma_f32_16x16x32_bf16(am[fm], bm_[fn], accm[fm][fn],0,0,0);
          accp[fm][fn] = __builtin_amdgcn_mfma_f32_16x16x32_bf16(ap[fm], bp_[fn], accp[fm][fn],0,0,0);
        }
    }
    __syncthreads();
  }
  int ro=(lane>>4)*4, co=lane&15;
  #pragma unroll
  for(int fm=0;fm<4;fm++){
    #pragma unroll
    for(int fn=0;fn<4;fn++){
      int col = wn*64 + fn*16 + co;
      #pragma unroll
      for(int r=0;r<4;r++){
        int row = m0 + wm*64 + fm*16 + ro + r;
        float mv = accm[fm][fn][r];
        float pv = accp[fm][fn][r];
        u16 o0, o1;
        if(z<2){
          float sn, cs;
          __sincosf(pv, &sn, &cs);
          o0 = f2bf(mv*cs); o1 = f2bf(mv*sn);
        } else {
          o0 = f2bf(mv); o1 = f2bf(pv);
        }
        u16* base = (z==0) ? (a.qpk + (size_t)row*512)
                           : (a.kvpk + (size_t)row*1024 + (z==2 ? 512 : 0));
        base[col] = o0;
        base[col+256] = o1;
      }
    }
  }
}

// ---------------- fused attention v3: cos-decomposed scores, streaming metadata ----------------
__global__ __launch_bounds__(256) void k_attn_fused(
    const int* __restrict__ rowptr, const int* __restrict__ srcp,
    const u16* __restrict__ qpack, const u16* __restrict__ kvpack,
    const u16* __restrict__ rbfp,
    const float* __restrict__ We, const float* __restrict__ be,
    float* __restrict__ nmag, float* __restrict__ nph,
    u16* __restrict__ npack)
{
  int wid = threadIdx.x >> 6, lane = threadIdx.x & 63;
  int hid = lane >> 5, l = lane & 31;
  int d = blockIdx.x*4 + wid;
  int b = rowptr[d], e = rowptr[d+1];
  const u16* qb = qpack + (size_t)d*512 + l*8;
  u16x8 qc8 = *(const u16x8*)qb;
  u16x8 qs8 = *(const u16x8*)(qb + 256);
  float qcf[8], qsf[8];
  #pragma unroll
  for(int j=0;j<8;j++){ qcf[j]=bf2f(qc8[j]); qsf[j]=bf2f(qs8[j]); }
  float We0 = (2*l   < NRBF) ? We[2*l]   : 0.f;
  float We1 = (2*l+1 < NRBF) ? We[2*l+1] : 0.f;
  float be0 = be[0];
  float z = 0.f;
  float avm[8] = {0,0,0,0,0,0,0,0}, avp[8] = {0,0,0,0,0,0,0,0};
  for(int i = b + hid; i < e; i += 2){
    int s = srcp[i];
    const u16* kb = kvpack + (size_t)s*1024 + l*8;
    u16x8 kc8 = *(const u16x8*)kb;
    u16x8 ks8 = *(const u16x8*)(kb + 256);
    u16x8 vm8 = *(const u16x8*)(kb + 512);
    u16x8 vp8 = *(const u16x8*)(kb + 768);
    u16x2 rb2 = *(const u16x2*)(rbfp + (size_t)i*64 + 2*l);
    float p = 0.f;
    #pragma unroll
    for(int j=0;j<8;j++){
      p = fmaf(qcf[j], bf2f(kc8[j]), p);
      p = fmaf(qsf[j], bf2f(ks8[j]), p);
    }
    float t = fmaf(bf2f(rb2[0]), We0, fmaf(bf2f(rb2[1]), We1, p*0.0625f));
    #pragma unroll
    for(int off=16; off; off>>=1) t += __shfl_xor(t, off, 64);
    float w = __expf(t + be0);   // scores O(1): softmax shift-invariant, no max needed
    z += w;
    #pragma unroll
    for(int j=0;j<8;j++){
      avm[j] = fmaf(w, bf2f(vm8[j]), avm[j]);
      avp[j] = fmaf(w, bf2f(vp8[j]), avp[j]);
    }
  }
  z += __shfl_xor(z, 32, 64);
  #pragma unroll
  for(int j=0;j<8;j++){
    avm[j] += __shfl_xor(avm[j], 32, 64);
    avp[j] += __shfl_xor(avp[j], 32, 64);
  }
  if(hid==0){
    float inv = 1.f/(z + 1e-9f);
    u16x8 mb, pb;
    #pragma unroll
    for(int j=0;j<8;j++){ avm[j]*=inv; avp[j]*=inv; mb[j]=f2bf(avm[j]); pb[j]=f2bf(avp[j]); }
    size_t no = (size_t)d*256 + l*8;
    *(float4*)(nmag + no)     = make_float4(avm[0],avm[1],avm[2],avm[3]);
    *(float4*)(nmag + no + 4) = make_float4(avm[4],avm[5],avm[6],avm[7]);
    *(float4*)(nph + no)      = make_float4(avp[0],avp[1],avp[2],avp[3]);
    *(float4*)(nph + no + 4)  = make_float4(avp[4],avp[5],avp[6],avp[7]);
    u16* nb = npack + (size_t)d*512 + l*8;
    *(u16x8*)nb = mb;
    *(u16x8*)(nb + 256) = pb;
  }
}

// ---------------- message passing aggregation v3 (streaming gate, packed gathers) ----------------
__global__ __launch_bounds__(256) void k_mp_agg(const int* __restrict__ rowptr,
                         const int* __restrict__ srcp, const u16* __restrict__ gate,
                         const u16* __restrict__ npack,
                         u16* __restrict__ aggm, u16* __restrict__ aggp){
  int wid = threadIdx.x >> 6, lane = threadIdx.x & 63;
  int hid = lane >> 5, l = lane & 31;
  int n = blockIdx.x*4 + wid;
  int b = rowptr[n], e = rowptr[n+1];
  float am[8] = {0,0,0,0,0,0,0,0}, ap[8] = {0,0,0,0,0,0,0,0};
  for(int i = b + hid; i < e; i += 2){
    int s = srcp[i];
    u16x8 g8 = *(const u16x8*)(gate + (size_t)i*256 + l*8);
    const u16* nb = npack + (size_t)s*512 + l*8;
    u16x8 m8 = *(const u16x8*)nb;
    u16x8 p8 = *(const u16x8*)(nb + 256);
    #pragma unroll
    for(int j=0;j<8;j++){
      float g = bf2f(g8[j]);
      am[j] = fmaf(g, bf2f(m8[j]), am[j]);
      ap[j] = fmaf(g, bf2f(p8[j]), ap[j]);
    }
  }
  #pragma unroll
  for(int j=0;j<8;j++){
    am[j] += __shfl_xor(am[j], 32, 64);
    ap[j] += __shfl_xor(ap[j], 32, 64);
  }
  if(hid==0){
    u16x8 amb, apb;
    #pragma unroll
    for(int j=0;j<8;j++){ amb[j]=f2bf(am[j]); apb[j]=f2bf(ap[j]); }
    size_t o = (size_t)n*256 + l*8;
    *(u16x8*)(aggm + o) = amb;
    *(u16x8*)(aggp + o) = apb;
  }
}

// ---------------- residual + LayerNorm (LAST fuses mag*cos(ph) projection input) ----------------
template<int LAST>
__global__ __launch_bounds__(256) void k_resid_ln(const float* __restrict__ nmag, const float* __restrict__ nph,
                           float* __restrict__ mag, float* __restrict__ ph,
                           u16* __restrict__ magb, u16* __restrict__ phb,
                           u16* __restrict__ tcosb,
                           const float* __restrict__ g, const float* __restrict__ b){
  int n = blockIdx.x, tid = threadIdx.x;
  size_t idx = (size_t)n*HDIM+tid;
  float t = nmag[idx] + mag[idx];
  float s1=t, s2=t*t;
  #pragma unroll
  for(int off=32; off; off>>=1){ s1 += __shfl_down(s1,off,64); s2 += __shfl_down(s2,off,64); }
  __shared__ float w1[4], w2[4], bc[2];
  int wid = tid>>6, lane = tid&63;
  if(lane==0){ w1[wid]=s1; w2[wid]=s2; }
  __syncthreads();
  if(tid==0){
    float a=w1[0]+w1[1]+w1[2]+w1[3];
    float q=w2[0]+w2[1]+w2[2]+w2[3];
    float mu = a*(1.f/HDIM);
    float var = q*(1.f/HDIM) - mu*mu;
    bc[0]=mu; bc[1]=rsqrtf(var+1e-5f);
  }
  __syncthreads();
  float mu=bc[0], rs=bc[1];
  float ln = (t-mu)*rs*g[tid]+b[tid];
  float p2 = nph[idx] + ph[idx];
  if(LAST){
    tcosb[idx] = f2bf(ln*__cosf(p2));
  } else {
    mag[idx] = ln; magb[idx] = f2bf(ln);
    ph[idx] = p2; phb[idx] = f2bf(p2);
  }
}

// ---------------- pooling ----------------
__global__ void k_pool(const float* __restrict__ arepr, const int* __restrict__ n2m,
                       float* __restrict__ spool, float* __restrict__ cntf){
  int gid = blockIdx.x*256+threadIdx.x;
  int n = gid>>8, h = gid&255;
  int m = n2m[n];
  atomicAdd(&spool[(size_t)m*HDIM+h], arepr[(size_t)n*HDIM+h]);
  if(h==0) atomicAdd(&cntf[m], 1.f);
}

// ---------------- head MLP ----------------
__global__ __launch_bounds__(256) void k_head(const float* __restrict__ spool, const float* __restrict__ cntf,
                       const float* __restrict__ W1, const float* __restrict__ b1,
                       const float* __restrict__ W2, const float* __restrict__ b2,
                       const float* __restrict__ W3, const float* __restrict__ b3,
                       float* __restrict__ out){
  __shared__ float smol[2*HDIM];
  __shared__ float sh1[HDIM];
  __shared__ float sh2[HDIM/2];
  int m = blockIdx.x, tid = threadIdx.x;
  float sv = spool[(size_t)m*HDIM+tid];
  float c = cntf[m];
  smol[tid] = sv/fmaxf(c,1.f);
  smol[HDIM+tid] = sv;
  __syncthreads();
  float a = b1[tid];
  for(int i=0;i<2*HDIM;i++) a = fmaf(smol[i], W1[i*HDIM+tid], a);
  sh1[tid] = siluf(a);
  __syncthreads();
  if(tid<128){
    float a2 = b2[tid];
    for(int i=0;i<HDIM;i++) a2 = fmaf(sh1[i], W2[i*128+tid], a2);
    sh2[tid] = siluf(a2);
  }
  __syncthreads();
  if(tid<64){
    float p = sh2[tid]*W3[tid] + sh2[tid+64]*W3[tid+64];
    #pragma unroll
    for(int off=32; off; off>>=1) p += __shfl_down(p,off,64);
    if(tid==0) out[m] = p + b3[0];
  }
}

extern "C" void kernel_launch(void* const* d_in, const int* in_sizes, int n_in,
                              void* d_out, int out_size, void* d_ws, size_t ws_size,
                              hipStream_t stream){
  const float* atom_types = (const float*)d_in[0];
  const float* coords     = (const float*)d_in[1];
  const float* edge_dist  = (const float*)d_in[2];
  const int*   edge_index = (const int*)d_in[3];
  const int*   node2mol   = (const int*)d_in[4];
  const float* emb_Wm = (const float*)d_in[5];
  const float* emb_bm = (const float*)d_in[6];
  const float* emb_Wp = (const float*)d_in[7];
  const float* emb_bp = (const float*)d_in[8];
  const float* attn_Wqm = (const float*)d_in[9];
  const float* attn_Wkm = (const float*)d_in[10];
  const float* attn_Wvm = (const float*)d_in[11];
  const float* attn_Wqp = (const float*)d_in[12];
  const float* attn_Wkp = (const float*)d_in[13];
  const float* attn_Wvp = (const float*)d_in[14];
  const float* attn_We  = (const float*)d_in[15];
  const float* attn_be  = (const float*)d_in[16];
  const float* mp_We = (const float*)d_in[17];
  const float* mp_be = (const float*)d_in[18];
  const float* mp_Wm = (const float*)d_in[19];
  const float* mp_bm = (const float*)d_in[20];
  const float* mp_Wp = (const float*)d_in[21];
  const float* mp_bp = (const float*)d_in[22];
  const float* ln_g = (const float*)d_in[23];
  const float* ln_b = (const float*)d_in[24];
  const float* proj_W = (const float*)d_in[25];
  const float* proj_b = (const float*)d_in[26];
  const float* head_W1 = (const float*)d_in[27];
  const float* head_b1 = (const float*)d_in[28];
  const float* head_W2 = (const float*)d_in[29];
  const float* head_b2 = (const float*)d_in[30];
  const float* head_W3 = (const float*)d_in[31];
  const float* head_b3 = (const float*)d_in[32];
  float* out = (float*)d_out;

  float* ws = (float*)d_ws;
  const size_t NH = (size_t)N_NODES*HDIM;
  size_t o = 0;
  float* mag = ws + o; o += NH;
  float* ph  = ws + o; o += NH;
  float* nmag= ws + o; o += NH;
  float* nph = ws + o; o += NH;
  float* spool = ws + o; o += (size_t)N_MOLS*HDIM;
  float* cntf  = ws + o; o += N_MOLS;
  int* rowptr = (int*)(ws + o); o += N_NODES+1;
  int* cnt    = (int*)(ws + o); o += N_NODES;
  int* cursor = (int*)(ws + o); o += N_NODES;
  int* perm   = (int*)(ws + o); o += N_EDGES;
  int* srcp   = (int*)(ws + o); o += N_EDGES + 1;   // +1 keeps 8B alignment after
  u16* magb = (u16*)(ws + o); o += NH/2;
  u16* phb  = (u16*)(ws + o); o += NH/2;
  u16* aggmb= (u16*)(ws + o); o += NH/2;
  u16* aggpb= (u16*)(ws + o); o += NH/2;
  u16* npack= (u16*)(ws + o); o += NH;                        // [N][512] bf16 (mag|ph)
  u16* rbfp = (u16*)(ws + o); o += (size_t)N_EDGES*32;        // [E][64] bf16, CSR order
  u16* qpack= (u16*)(ws + o); o += NH;                        // [N][512] bf16 (qc|qs)
  u16* kvpack=(u16*)(ws + o); o += 2*NH;                      // [N][1024] bf16 (kc|ks|vm|vp)
  o += NH;                                                    // pad: gatep tail
  u16* wt   = (u16*)(ws + o); o += (25*(size_t)HH + 3*HDIM*64)/2;
  u16* gatep = qpack;      // [E][256] bf16 CSR order; aliases qpack+kvpack+pad (disjoint lifetime)
  float* arepr = nmag;     // free after last resid_ln
  u16* tcosb = aggmb;      // free after last mp gemm

  const int* src = edge_index;
  const int* dst = edge_index + N_EDGES;

  // ---- weight convert/transpose descriptors ----
  WArgs wa;
  for(int l=0;l<NLAYER;l++){
    const float* srcs[6] = {attn_Wqm+(size_t)l*HH, attn_Wkm+(size_t)l*HH, attn_Wvm+(size_t)l*HH,
                            attn_Wqp+(size_t)l*HH, attn_Wkp+(size_t)l*HH, attn_Wvp+(size_t)l*HH};
    for(int j=0;j<6;j++){ wa.d[l*6+j] = { srcs[j], wt + (size_t)(l*6+j)*HH, HDIM, HDIM }; }
    wa.d[18+l] = { mp_Wm+(size_t)l*HH, wt + (size_t)(18+l)*HH, HDIM, HDIM };
    wa.d[21+l] = { mp_Wp+(size_t)l*HH, wt + (size_t)(21+l)*HH, HDIM, HDIM };
    wa.d[25+l] = { mp_We+(size_t)l*NRBF*HDIM, wt + (size_t)25*HH + (size_t)l*HDIM*64, NRBF, 64 };
  }
  wa.d[24] = { proj_W, wt + (size_t)24*HH, HDIM, HDIM };

  hipMemsetAsync(cnt, 0, N_NODES*sizeof(int), stream);
  k_hist<<<N_EDGES/256,256,0,stream>>>(dst, cnt);
  k_scan<<<1,1024,0,stream>>>(cnt, rowptr, cursor);
  k_scatter<<<N_EDGES/256,256,0,stream>>>(dst, src, cursor, perm, srcp);
  k_wconv<<<dim3(28,64),256,0,stream>>>(wa);
  k_rbf<<<(N_EDGES*64)/256,256,0,stream>>>(edge_dist, perm, rbfp);
  k_embed<<<N_NODES,256,0,stream>>>(atom_types, coords, emb_Wm, emb_bm, emb_Wp, emb_bp,
                                    mag, ph, magb, phb);

  for(int l=0;l<NLAYER;l++){
    Qkv3Args qa;
    qa.Wm[0] = wt + (size_t)(l*6+0)*HH;  // Wqm
    qa.Wm[1] = wt + (size_t)(l*6+1)*HH;  // Wkm
    qa.Wm[2] = wt + (size_t)(l*6+2)*HH;  // Wvm
    qa.Wp[0] = wt + (size_t)(l*6+3)*HH;  // Wqp
    qa.Wp[1] = wt + (size_t)(l*6+4)*HH;  // Wkp
    qa.Wp[2] = wt + (size_t)(l*6+5)*HH;  // Wvp
    qa.qpk = qpack; qa.kvpk = kvpack;
    k_gemm_qkv3<<<dim3(1,N_NODES/128,3),512,0,stream>>>(magb, phb, qa);
    k_attn_fused<<<N_NODES/4,256,0,stream>>>(rowptr, srcp, qpack, kvpack,
                                             rbfp, attn_We+(size_t)l*NRBF, attn_be+l,
                                             nmag, nph, npack);
    k_gemm_gate<<<dim3(1,N_EDGES/128),512,0,stream>>>(rbfp, wt + (size_t)25*HH + (size_t)l*HDIM*64,
                                                      mp_be+(size_t)l*HDIM, gatep);
    k_mp_agg<<<N_NODES/4,256,0,stream>>>(rowptr, srcp, gatep, npack, aggmb, aggpb);
    MpArgs ma;
    ma.A[0]=aggmb; ma.A[1]=aggpb;
    ma.Wt[0]=wt + (size_t)(18+l)*HH; ma.Wt[1]=wt + (size_t)(21+l)*HH;
    ma.b[0]=mp_bm+(size_t)l*HDIM; ma.b[1]=mp_bp+(size_t)l*HDIM;
    ma.C[0]=nmag; ma.C[1]=nph;
    k_gemm_mp<<<dim3(1,N_NODES/128,2),512,0,stream>>>(ma);
    if(l < NLAYER-1)
      k_resid_ln<0><<<N_NODES,256,0,stream>>>(nmag, nph, mag, ph, magb, phb, nullptr,
                                              ln_g+(size_t)l*HDIM, ln_b+(size_t)l*HDIM);
    else
      k_resid_ln<1><<<N_NODES,256,0,stream>>>(nmag, nph, mag, ph, magb, phb, tcosb,
                                              ln_g+(size_t)l*HDIM, ln_b+(size_t)l*HDIM);
  }
  k_gemm_proj<<<dim3(1,N_NODES/128),512,0,stream>>>(tcosb, wt + (size_t)24*HH, proj_b, arepr);
  hipMemsetAsync(spool, 0, ((size_t)N_MOLS*HDIM+N_MOLS)*sizeof(float), stream);
  k_pool<<<NH/256,256,0,stream>>>(arepr, node2mol, spool, cntf);
  k_head<<<N_MOLS,256,0,stream>>>(spool, cntf, head_W1, head_b1, head_W2, head_b2, head_W3, head_b3, out);
}